// Round 1
// baseline (1259.570 us; speedup 1.0000x reference)
//
#include <hip/hip_runtime.h>
#include <math.h>

// PropagationBlock: GNN edge-message propagation, NV=32, DIM=3.
// Algebra: edge-side matmuls folded into P,Q; node-side into R,S.

#define NV 32

__device__ __forceinline__ float silu_f(float x) { return x / (1.0f + __expf(-x)); }

// ---------------------------------------------------------------- kernel 0
// P = C1+C2, Q = C2-C1 with C1=(n2e_M1@Mvv)/2, C2=(n2e_M2@Mvv)/4, Mvv=(vv1+vv2)/2
// R = (e2n_M1+e2n_M2)/2, S = (e2n_M2-e2n_M1)/2
__global__ __launch_bounds__(1024) void prep_mats_kernel(
    const float* __restrict__ n2e_M1, const float* __restrict__ n2e_M2,
    const float* __restrict__ vv_M1, const float* __restrict__ vv_M2,
    const float* __restrict__ e2n_M1, const float* __restrict__ e2n_M2,
    float* __restrict__ PQRS) {
  __shared__ float Mvv[32][32];
  int j = threadIdx.x & 31, i = threadIdx.x >> 5;
  Mvv[i][j] = 0.5f * (vv_M1[i * 32 + j] + vv_M2[i * 32 + j]);
  __syncthreads();
  float c1 = 0.f, c2 = 0.f;
#pragma unroll
  for (int k = 0; k < 32; k++) {
    c1 += n2e_M1[i * 32 + k] * Mvv[k][j];
    c2 += n2e_M2[i * 32 + k] * Mvv[k][j];
  }
  c1 *= 0.5f;
  c2 *= 0.25f;
  PQRS[0 * 1024 + i * 32 + j] = c1 + c2;                                  // P
  PQRS[1 * 1024 + i * 32 + j] = c2 - c1;                                  // Q
  PQRS[2 * 1024 + i * 32 + j] = 0.5f * (e2n_M1[i * 32 + j] + e2n_M2[i * 32 + j]); // R
  PQRS[3 * 1024 + i * 32 + j] = 0.5f * (e2n_M2[i * 32 + j] - e2n_M1[i * 32 + j]); // S
}

// ---------------------------------------------------------------- kernel 1
// xn2 = cos(a)*xn + sin(a)*(((xn@M) * attr) @ M^T)   ; 32 lanes per node
__global__ __launch_bounds__(256) void node_premix_kernel(
    const float* __restrict__ xn, const float* __restrict__ xn_attr,
    const float* __restrict__ ms_M, const float* __restrict__ ms_w,
    float* __restrict__ xn2, int n_nodes) {
  __shared__ float M[32][33];  // padded: row-read M[lane][s] must be conflict-free
  for (int idx = threadIdx.x; idx < 1024; idx += blockDim.x)
    M[idx >> 5][idx & 31] = ms_M[idx];
  __syncthreads();

  int lane = threadIdx.x & 31;
  int grp = blockIdx.x * (blockDim.x >> 5) + (threadIdx.x >> 5);
  if (grp >= n_nodes) return;

  float angle = 0.1f * ms_w[0];
  float ca = cosf(angle), sa = sinf(angle);

  const float* xp = xn + (size_t)grp * 96;
  float x0 = xp[lane], x1 = xp[32 + lane], x2 = xp[64 + lane];

  // t[d][s=lane] = sum_v x[d][v] * M[v][s]
  float t0 = 0.f, t1 = 0.f, t2 = 0.f;
#pragma unroll
  for (int v = 0; v < 32; v++) {
    float m = M[v][lane];
    t0 += __shfl(x0, v, 32) * m;
    t1 += __shfl(x1, v, 32) * m;
    t2 += __shfl(x2, v, 32) * m;
  }
  float attr = xn_attr[(size_t)grp * 32 + lane];
  t0 *= attr; t1 *= attr; t2 *= attr;

  // y[d][v=lane] = sum_s t[d][s] * M[lane][s]
  float y0 = 0.f, y1 = 0.f, y2 = 0.f;
#pragma unroll
  for (int s = 0; s < 32; s++) {
    float m = M[lane][s];
    y0 += __shfl(t0, s, 32) * m;
    y1 += __shfl(t1, s, 32) * m;
    y2 += __shfl(t2, s, 32) * m;
  }

  float* op = xn2 + (size_t)grp * 96;
  op[lane]      = ca * x0 + sa * y0;
  op[32 + lane] = ca * x1 + sa * y1;
  op[64 + lane] = ca * x2 + sa * y2;
}

// ---------------------------------------------------------------- kernel 2
// per edge: w1=silu(ea*fc1w+fc1b); g = (w1*xs)@P + (w1*xd)@Q; wxe = w2*g;
// atomic scatter: acc1[dst]+=wxe, acc2[src]+=wxe
__global__ __launch_bounds__(256) void edge_kernel(
    const float* __restrict__ xn2, const float* __restrict__ xe_attr,
    const int* __restrict__ xe_src, const int* __restrict__ xe_dst,
    const float* __restrict__ fc1_w, const float* __restrict__ fc1_b,
    const float* __restrict__ fc2_w, const float* __restrict__ fc2_b,
    const float* __restrict__ Pg, const float* __restrict__ Qg,
    float* __restrict__ acc1, float* __restrict__ acc2, int n_edges) {
  __shared__ float P[32][32], Q[32][32];
  for (int idx = threadIdx.x; idx < 1024; idx += blockDim.x) {
    P[idx >> 5][idx & 31] = Pg[idx];
    Q[idx >> 5][idx & 31] = Qg[idx];
  }
  __syncthreads();

  int lane = threadIdx.x & 31;
  int egrp = blockIdx.x * (blockDim.x >> 5) + (threadIdx.x >> 5);
  int estride = gridDim.x * (blockDim.x >> 5);

  float f1w = fc1_w[lane], f1b = fc1_b[lane];
  float f2w = fc2_w[lane], f2b = fc2_b[lane];

  for (int e = egrp; e < n_edges; e += estride) {
    float ea = xe_attr[e];
    float w1 = silu_f(ea * f1w + f1b);
    float w2 = silu_f(ea * f2w + f2b);
    int sn = xe_src[e], dn = xe_dst[e];
    const float* xs = xn2 + (size_t)sn * 96;
    const float* xd = xn2 + (size_t)dn * 96;
    float a0 = w1 * xs[lane], a1 = w1 * xs[32 + lane], a2 = w1 * xs[64 + lane];
    float b0 = w1 * xd[lane], b1 = w1 * xd[32 + lane], b2 = w1 * xd[64 + lane];

    float g0 = 0.f, g1 = 0.f, g2 = 0.f;
#pragma unroll
    for (int v = 0; v < 32; v++) {
      float p = P[v][lane], q = Q[v][lane];
      g0 += __shfl(a0, v, 32) * p + __shfl(b0, v, 32) * q;
      g1 += __shfl(a1, v, 32) * p + __shfl(b1, v, 32) * q;
      g2 += __shfl(a2, v, 32) * p + __shfl(b2, v, 32) * q;
    }
    g0 *= w2; g1 *= w2; g2 *= w2;

    float* p1 = acc1 + (size_t)dn * 96;
    float* p2 = acc2 + (size_t)sn * 96;
    atomicAdd(&p1[lane], g0);
    atomicAdd(&p1[32 + lane], g1);
    atomicAdd(&p1[64 + lane], g2);
    atomicAdd(&p2[lane], g0);
    atomicAdd(&p2[32 + lane], g1);
    atomicAdd(&p2[64 + lane], g2);
  }
}

// ---------------------------------------------------------------- kernel 3
// out = acc1@R + acc2@S, then x * tanh(||x||_dim)
__global__ __launch_bounds__(256) void node_post_kernel(
    const float* __restrict__ acc1, const float* __restrict__ acc2,
    const float* __restrict__ Rg, const float* __restrict__ Sg,
    float* __restrict__ out, int n_nodes) {
  __shared__ float R[32][32], S[32][32];
  for (int idx = threadIdx.x; idx < 1024; idx += blockDim.x) {
    R[idx >> 5][idx & 31] = Rg[idx];
    S[idx >> 5][idx & 31] = Sg[idx];
  }
  __syncthreads();

  int lane = threadIdx.x & 31;
  int grp = blockIdx.x * (blockDim.x >> 5) + (threadIdx.x >> 5);
  if (grp >= n_nodes) return;

  const float* a = acc1 + (size_t)grp * 96;
  const float* b = acc2 + (size_t)grp * 96;
  float a0 = a[lane], a1 = a[32 + lane], a2 = a[64 + lane];
  float b0 = b[lane], b1 = b[32 + lane], b2 = b[64 + lane];

  float y0 = 0.f, y1 = 0.f, y2 = 0.f;
#pragma unroll
  for (int v = 0; v < 32; v++) {
    float r = R[v][lane], s = S[v][lane];
    y0 += __shfl(a0, v, 32) * r + __shfl(b0, v, 32) * s;
    y1 += __shfl(a1, v, 32) * r + __shfl(b1, v, 32) * s;
    y2 += __shfl(a2, v, 32) * r + __shfl(b2, v, 32) * s;
  }

  float nrm = sqrtf(y0 * y0 + y1 * y1 + y2 * y2);
  float t = tanhf(nrm);

  float* op = out + (size_t)grp * 96;
  op[lane]      = y0 * t;
  op[32 + lane] = y1 * t;
  op[64 + lane] = y2 * t;
}

// ---------------------------------------------------------------- launch
extern "C" void kernel_launch(void* const* d_in, const int* in_sizes, int n_in,
                              void* d_out, int out_size, void* d_ws, size_t ws_size,
                              hipStream_t stream) {
  const float* xn      = (const float*)d_in[0];
  const float* xn_attr = (const float*)d_in[1];
  const float* xe_attr = (const float*)d_in[2];
  const int*   xe_src  = (const int*)d_in[3];
  const int*   xe_dst  = (const int*)d_in[4];
  const float* ms_M    = (const float*)d_in[5];
  const float* ms_w    = (const float*)d_in[6];
  const float* fc1_w   = (const float*)d_in[7];
  const float* fc1_b   = (const float*)d_in[8];
  const float* fc2_w   = (const float*)d_in[9];
  const float* fc2_b   = (const float*)d_in[10];
  const float* n2e_M1  = (const float*)d_in[11];
  const float* n2e_M2  = (const float*)d_in[12];
  const float* vv_M1   = (const float*)d_in[13];
  const float* vv_M2   = (const float*)d_in[14];
  const float* e2n_M1  = (const float*)d_in[15];
  const float* e2n_M2  = (const float*)d_in[16];

  int n_nodes = in_sizes[0] / 96;
  int n_edges = in_sizes[2];

  float* ws   = (float*)d_ws;
  float* PQRS = ws;                                  // 4096 floats (16 KB)
  float* acc1 = ws + 4096;                           // n_nodes*96
  float* acc2 = acc1 + (size_t)n_nodes * 96;         // n_nodes*96
  float* xn2  = (float*)d_out;                       // reuse d_out as scratch for mixed nodes

  prep_mats_kernel<<<1, 1024, 0, stream>>>(n2e_M1, n2e_M2, vv_M1, vv_M2, e2n_M1, e2n_M2, PQRS);

  int nblk = (n_nodes + 7) / 8;  // 8 nodes (32 lanes each) per 256-thread block
  node_premix_kernel<<<nblk, 256, 0, stream>>>(xn, xn_attr, ms_M, ms_w, xn2, n_nodes);

  hipMemsetAsync(acc1, 0, (size_t)n_nodes * 96 * 2 * sizeof(float), stream);

  edge_kernel<<<4096, 256, 0, stream>>>(xn2, xe_attr, xe_src, xe_dst,
                                        fc1_w, fc1_b, fc2_w, fc2_b,
                                        PQRS, PQRS + 1024, acc1, acc2, n_edges);

  node_post_kernel<<<nblk, 256, 0, stream>>>(acc1, acc2, PQRS + 2048, PQRS + 3072,
                                             (float*)d_out, n_nodes);
}